// Round 5
// baseline (93.235 us; speedup 1.0000x reference)
//
#include <hip/hip_runtime.h>

// 3-phase windowed-bitmask NMS (bit-exact vs the JAX reference):
//  P1 rank_kernel : stable argsort(-scores) via comparison counting.
//  P2 mask_kernel : suppression bit-rows for the top kM x kM window.
//  P3 scan_kernel : greedy scan, 64-row chunks resolved via ballot fixpoint
//                   (IoU symmetry gives each lane its in-chunk suppressor
//                   column from the row's diagonal words) — no per-row shfl.
//                   Lazy exact continuation past the window if ever needed.
// Falls back to a single-kernel version if ws is too small.
// (Resubmission of round-4 source — container died before benching.)

constexpr int   kN      = 2048;
constexpr int   kM      = 640;     // mask window (rows & cols), multiple of 64
constexpr int   kNCH    = kM / 64; // chunks of 64 rows
constexpr float kIouThr = 0.7f;

// ---------------------------------------------------------------- P1: rank
constexpr int kRankThreads = 256;          // 128 rows/block, 2 threads/row

__global__ __launch_bounds__(kRankThreads)
void rank_kernel(const float* __restrict__ rois,    // [B, kN, 4]
                 const float* __restrict__ scores,  // [B, kN]
                 int* __restrict__ order,           // [B, kN] ws
                 float4* __restrict__ boxes_sorted) // [B, kN] ws (canonical)
{
    const int b  = blockIdx.y;
    const int r0 = blockIdx.x * (kRankThreads / 2);

    __shared__ float s_score[kN];
    const float* bs = scores + (size_t)b * kN;
    for (int t = threadIdx.x; t < kN; t += kRankThreads) s_score[t] = bs[t];
    __syncthreads();

    const int   row  = r0 + (threadIdx.x >> 1);
    const int   half = threadIdx.x & 1;
    const float si   = s_score[row];

    int rank = 0;
    const float4* s4 = reinterpret_cast<const float4*>(s_score);
    const int j4b = half * (kN / 8), j4e = j4b + kN / 8;
    for (int j4 = j4b; j4 < j4e; ++j4) {
        const float4 v = s4[j4];
        const int j = j4 * 4;
        rank += (v.x > si) || (v.x == si && (j + 0) < row);
        rank += (v.y > si) || (v.y == si && (j + 1) < row);
        rank += (v.z > si) || (v.z == si && (j + 2) < row);
        rank += (v.w > si) || (v.w == si && (j + 3) < row);
    }
    const int total = rank + __shfl_xor(rank, 1);

    if (half == 0) {
        order[(size_t)b * kN + total] = row;
        const float4 bx = reinterpret_cast<const float4*>(rois)[(size_t)b * kN + row];
        const float cy1 = fminf(bx.x, bx.z), cy2 = fmaxf(bx.x, bx.z);
        const float cx1 = fminf(bx.y, bx.w), cx2 = fmaxf(bx.y, bx.w);
        boxes_sorted[(size_t)b * kN + total] = make_float4(cy1, cx1, cy2, cx2);
    }
}

// ---------------------------------------------------------------- P2: mask
constexpr int kMaskThreads = 1024;          // 16 waves
constexpr int kRowsPerMaskBlock = 32;       // 2 rows per wave

__global__ __launch_bounds__(kMaskThreads)
void mask_kernel(const float4* __restrict__ boxes_sorted, // [B, kN]
                 unsigned int* __restrict__ mask)         // [B, kM, 64]
{
    const int b  = blockIdx.y;
    const int r0 = blockIdx.x * kRowsPerMaskBlock;

    __shared__ float4 s_box[kM];
    __shared__ float  s_area[kM];
    for (int t = threadIdx.x; t < kM; t += kMaskThreads) {
        const float4 c = boxes_sorted[(size_t)b * kN + t];
        s_box[t]  = c;
        s_area[t] = (c.z - c.x) * (c.w - c.y);
    }
    __syncthreads();

    const int wave = threadIdx.x >> 6;
    const int lane = threadIdx.x & 63;

    for (int rr = 0; rr < 2; ++rr) {
        const int i = r0 + wave * 2 + rr;          // i < kM
        const float4 bi = s_box[i];
        const float  ai = s_area[i];
        unsigned int myw = 0u;
        const int k0 = i >> 6;
        for (int k = k0; k < kM / 64; ++k) {
            const int j = k * 64 + lane;
            const float4 bj = s_box[j];
            const float iy1 = fmaxf(bi.x, bj.x);
            const float ix1 = fmaxf(bi.y, bj.y);
            const float iy2 = fminf(bi.z, bj.z);
            const float ix2 = fminf(bi.w, bj.w);
            const float inter = fmaxf(iy2 - iy1, 0.0f) * fmaxf(ix2 - ix1, 0.0f);
            const float uni   = ai + s_area[j] - inter;
            const bool  sup   = (uni > 0.0f) && (inter / uni > kIouThr);
            const unsigned long long bal = __ballot(sup);   // bit l <-> j=k*64+l
            if ((lane >> 1) == k)
                myw = (lane & 1) ? (unsigned int)(bal >> 32) : (unsigned int)bal;
        }
        mask[((size_t)b * kM + i) * 64 + lane] = myw;       // lanes >= kM/32 -> 0
    }
}

// ---------------------------------------------------------------- P3: scan
__global__ __launch_bounds__(64)
void scan_kernel(const unsigned int* __restrict__ mask,    // [B, kM, 64]
                 const int* __restrict__ order,            // [B, kN]
                 const float4* __restrict__ boxes_sorted,  // [B, kN] canonical
                 const float* __restrict__ rois,           // [B, kN, 4] orig
                 float* __restrict__ out,                  // [B, max_out, 4]
                 int max_out)
{
    const int b    = blockIdx.x;
    const int lane = threadIdx.x;
    const unsigned int* m = mask + (size_t)b * kM * 64;

    __shared__ int    s_keep[512];      // kept sorted-positions (max_out<=512)
    __shared__ float4 s_kbox[512];      // kept canonical boxes (fallback only)
    __shared__ float  s_karea[512];

    unsigned int sup = 0u;              // lane w owns suppression word w
    int count = 0;
    unsigned long long prev64 = 0ull;   // suppression bits of current chunk rows
    bool stopped = false;

    unsigned int bufA[64], bufB[64];
    unsigned int dAlo = 0, dAhi = 0, dBlo = 0, dBhi = 0;

    // Load 64 rows of the chunk (lane = column word) + the 2 diagonal words
    // of row (base+lane); by exact IoU symmetry those form this lane's
    // in-chunk suppressor COLUMN.
#define PREFETCH(BUF, DLO, DHI, CH) {                                         \
        const int base_ = (CH) * 64;                                          \
        _Pragma("unroll")                                                     \
        for (int t = 0; t < 64; ++t)                                          \
            BUF[t] = m[(size_t)(base_ + t) * 64 + lane];                      \
        DLO = m[(size_t)(base_ + lane) * 64 + 2 * (CH)];                      \
        DHI = m[(size_t)(base_ + lane) * 64 + 2 * (CH) + 1];                  \
    }

#define RESOLVE(BUF, DLO, DHI, CH) {                                          \
        const int base_ = (CH) * 64;                                          \
        const unsigned long long mycol =                                      \
            (unsigned long long)(DLO) | ((unsigned long long)(DHI) << 32);    \
        unsigned long long notSup = ~prev64;                                  \
        unsigned long long todo   = ~0ull;                                    \
        unsigned long long kept   = 0ull;                                     \
        while (count < max_out) {                                             \
            const unsigned long long cand = notSup & todo;    /* uniform */   \
            if (!cand) break;                                                 \
            const int u = __builtin_ctzll(cand);  /* lowest undecided=KEPT */ \
            if (lane == 0) s_keep[count] = base_ + u;                         \
            ++count;                                                          \
            kept |= (1ull << u);                                              \
            const unsigned long long low =                                    \
                (u == 63) ? ~0ull : ((1ull << (u + 1)) - 1ull);               \
            todo &= ~low;                                                     \
            const unsigned long long supByU = __ballot((mycol >> u) & 1ull);  \
            notSup &= ~(supByU & ~low);          /* suppress rows > u only */ \
        }                                                                     \
        if (count >= max_out) { stopped = true; }                             \
        else {                                                                \
            _Pragma("unroll")                                                 \
            for (int t = 0; t < 64; ++t)                                      \
                if ((kept >> t) & 1) sup |= BUF[t];   /* kept rows only */    \
            const unsigned int w0_ = __shfl((int)sup, 2 * ((CH) + 1));        \
            const unsigned int w1_ = __shfl((int)sup, 2 * ((CH) + 1) + 1);    \
            prev64 = (unsigned long long)w0_ |                                \
                     ((unsigned long long)w1_ << 32);                         \
        }                                                                     \
    }

    PREFETCH(bufA, dAlo, dAhi, 0)
    for (int ch = 0; ch < kNCH && !stopped; ch += 2) {
        if (ch + 1 < kNCH) PREFETCH(bufB, dBlo, dBhi, ch + 1)
        RESOLVE(bufA, dAlo, dAhi, ch)
        if (stopped) break;
        if (ch + 2 < kNCH) PREFETCH(bufA, dAlo, dAhi, ch + 2)
        if (ch + 1 < kNCH) RESOLVE(bufB, dBlo, dBhi, ch + 1)
    }
#undef PREFETCH
#undef RESOLVE

    // ---- lazy continuation past the window (correctness insurance) ----
    if (count < max_out) {
        __syncthreads();
        const float4* bsrt = boxes_sorted + (size_t)b * kN;
        for (int k = lane; k < count; k += 64) {
            const float4 c = bsrt[s_keep[k]];
            s_kbox[k]  = c;
            s_karea[k] = (c.z - c.x) * (c.w - c.y);
        }
        __syncthreads();
        for (int i = kM; i < kN && count < max_out; ++i) {
            const float4 bi = bsrt[i];
            const float  ai = (bi.z - bi.x) * (bi.w - bi.y);
            bool supb = false;
            for (int k = lane; k < count; k += 64) {
                const float4 bk = s_kbox[k];
                const float iy1 = fmaxf(bi.x, bk.x);
                const float ix1 = fmaxf(bi.y, bk.y);
                const float iy2 = fminf(bi.z, bk.z);
                const float ix2 = fminf(bi.w, bk.w);
                const float inter = fmaxf(iy2 - iy1, 0.0f) * fmaxf(ix2 - ix1, 0.0f);
                const float uni   = s_karea[k] + ai - inter;  // f32 add commutes
                supb = supb || ((uni > 0.0f) && (inter / uni > kIouThr));
            }
            if (!__any(supb)) {
                if (lane == 0) {
                    s_keep[count]  = i;
                    s_kbox[count]  = bi;
                    s_karea[count] = ai;
                }
                ++count;
            }
        }
    }

    __syncthreads();

    const float4* rois4 = reinterpret_cast<const float4*>(rois) + (size_t)b * kN;
    float4*       out4  = reinterpret_cast<float4*>(out) + (size_t)b * max_out;
    const int*    bo    = order + (size_t)b * kN;
    for (int c = lane; c < max_out; c += 64) {
        int oidx = 0;                                   // pad with orig box 0
        if (c < count) oidx = bo[s_keep[c]];
        out4[c] = rois4[oidx];
    }
}

// ------------------------------------------------- fallback (round-1 kernel)
constexpr int kFbThreads = 1024;

__global__ __launch_bounds__(kFbThreads)
void nms_fallback(const float* __restrict__ rois, const float* __restrict__ scores,
                  float* __restrict__ out, int max_out)
{
    const int b   = blockIdx.x;
    const int tid = threadIdx.x;
    __shared__ float        s_score[kN];
    __shared__ int          s_order[kN];
    __shared__ float4       s_box[kN];
    __shared__ float        s_area[kN];
    __shared__ unsigned int s_sup[kN / 32];
    __shared__ int          s_count;
    const float* brois   = rois   + (size_t)b * kN * 4;
    const float* bscores = scores + (size_t)b * kN;
    for (int i = tid; i < kN; i += kFbThreads) s_score[i] = bscores[i];
    for (int i = tid; i < kN / 32; i += kFbThreads) s_sup[i] = 0u;
    if (tid == 0) s_count = 0;
    __syncthreads();
    for (int i = tid; i < kN; i += kFbThreads) {
        const float si = s_score[i];
        int rank = 0;
        const float4* s4 = reinterpret_cast<const float4*>(s_score);
        for (int j4 = 0; j4 < kN / 4; ++j4) {
            const float4 v = s4[j4];
            const int j = j4 * 4;
            rank += (v.x > si) || (v.x == si && (j + 0) < i);
            rank += (v.y > si) || (v.y == si && (j + 1) < i);
            rank += (v.z > si) || (v.z == si && (j + 2) < i);
            rank += (v.w > si) || (v.w == si && (j + 3) < i);
        }
        s_order[rank] = i;
    }
    __syncthreads();
    for (int r = tid; r < kN; r += kFbThreads) {
        const int idx = s_order[r];
        const float4 bx = *reinterpret_cast<const float4*>(brois + (size_t)idx * 4);
        const float cy1 = fminf(bx.x, bx.z), cy2 = fmaxf(bx.x, bx.z);
        const float cx1 = fminf(bx.y, bx.w), cx2 = fmaxf(bx.y, bx.w);
        s_box[r]  = make_float4(cy1, cx1, cy2, cx2);
        s_area[r] = (cy2 - cy1) * (cx2 - cx1);
    }
    __syncthreads();
    for (int i = 0; i < kN; ++i) {
        const bool sup_i = (s_sup[i >> 5] >> (i & 31)) & 1u;
        if (!sup_i) {
            const float4 bi = s_box[i];
            const float  ai = s_area[i];
            for (int j = i + 1 + tid; j < kN; j += kFbThreads) {
                const float4 bj = s_box[j];
                const float iy1 = fmaxf(bi.x, bj.x);
                const float ix1 = fmaxf(bi.y, bj.y);
                const float iy2 = fminf(bi.z, bj.z);
                const float ix2 = fminf(bi.w, bj.w);
                const float inter = fmaxf(iy2 - iy1, 0.0f) * fmaxf(ix2 - ix1, 0.0f);
                const float uni   = ai + s_area[j] - inter;
                const float iou   = (uni > 0.0f) ? (inter / uni) : 0.0f;
                if (iou > kIouThr) atomicOr(&s_sup[j >> 5], 1u << (j & 31));
            }
            if (tid == 0) {
                const int c = s_count;
                if (c < max_out) {
                    const int oidx = s_order[i];
                    reinterpret_cast<float4*>(out)[(size_t)b * max_out + c] =
                        *reinterpret_cast<const float4*>(brois + (size_t)oidx * 4);
                }
                s_count = c + 1;
            }
        }
        __syncthreads();
        const bool stop = (s_count >= max_out);
        __syncthreads();
        if (stop) break;
    }
    const int c = min(s_count, max_out);
    const float4 pad = *reinterpret_cast<const float4*>(brois);
    for (int r = c + tid; r < max_out; r += kFbThreads) {
        reinterpret_cast<float4*>(out)[(size_t)b * max_out + r] = pad;
    }
}

// ---------------------------------------------------------------- launch
extern "C" void kernel_launch(void* const* d_in, const int* in_sizes, int n_in,
                              void* d_out, int out_size, void* d_ws, size_t ws_size,
                              hipStream_t stream)
{
    const float* rois   = (const float*)d_in[0];
    const float* scores = (const float*)d_in[1];
    float* out = (float*)d_out;

    const int B       = in_sizes[1] / kN;        // scores are [B, kN]
    const int max_out = out_size / (4 * B);      // out is [B, max_out, 4]

    const size_t maskBytes  = (size_t)B * kM * 64 * sizeof(unsigned int);
    const size_t orderBytes = (size_t)B * kN * sizeof(int);
    const size_t boxesBytes = (size_t)B * kN * sizeof(float4);

    if (ws_size >= maskBytes + orderBytes + boxesBytes && max_out <= 512) {
        unsigned int* mask  = (unsigned int*)d_ws;
        int*          order = (int*)((char*)d_ws + maskBytes);
        float4*       boxes = (float4*)((char*)d_ws + maskBytes + orderBytes);

        rank_kernel<<<dim3(kN / (kRankThreads / 2), B), dim3(kRankThreads), 0, stream>>>(
            rois, scores, order, boxes);
        mask_kernel<<<dim3(kM / kRowsPerMaskBlock, B), dim3(kMaskThreads), 0, stream>>>(
            boxes, mask);
        scan_kernel<<<dim3(B), dim3(64), 0, stream>>>(mask, order, boxes, rois, out, max_out);
    } else {
        nms_fallback<<<dim3(B), dim3(kFbThreads), 0, stream>>>(rois, scores, out, max_out);
    }
}

// Round 6
// 71.139 us; speedup vs baseline: 1.3106x; 1.3106x over previous
//
#include <hip/hip_runtime.h>

// 3-phase windowed-bitmask NMS (bit-exact vs the JAX reference):
//  P1 rank_kernel : stable argsort(-scores) via comparison counting.
//  P2 mask_kernel : FULL suppression bit-rows (incl. left of diagonal) for the
//                   top kM rows, compact [kM][20] words (kM/32 = 20).
//  P3 scan_kernel : greedy scan. Kept-bitmap = 20 uniform scalars; row r's
//                   "suppressed by earlier kept" test reads r's OWN row words
//                   (exact IoU symmetry) -> AND with kept words -> ballot.
//                   In-chunk resolution via ballot fixpoint on diagonal words.
//                   All register state statically indexed (no arrays -> no
//                   scratch spill, the round-5 regression).
//                   Lazy exact continuation past the window if ever needed.
// Falls back to a single-kernel version if ws is too small.

constexpr int   kN      = 2048;
constexpr int   kM      = 640;      // mask window rows/cols, multiple of 64
constexpr int   kNCH    = kM / 64;  // 10 chunks of 64 rows
constexpr int   kMW     = kM / 32;  // 20 mask words per row
constexpr float kIouThr = 0.7f;

// ---------------------------------------------------------------- P1: rank
constexpr int kRankThreads = 256;          // 128 rows/block, 2 threads/row

__global__ __launch_bounds__(kRankThreads)
void rank_kernel(const float* __restrict__ rois,    // [B, kN, 4]
                 const float* __restrict__ scores,  // [B, kN]
                 int* __restrict__ order,           // [B, kN] ws
                 float4* __restrict__ boxes_sorted) // [B, kN] ws (canonical)
{
    const int b  = blockIdx.y;
    const int r0 = blockIdx.x * (kRankThreads / 2);

    __shared__ float s_score[kN];
    const float* bs = scores + (size_t)b * kN;
    for (int t = threadIdx.x; t < kN; t += kRankThreads) s_score[t] = bs[t];
    __syncthreads();

    const int   row  = r0 + (threadIdx.x >> 1);
    const int   half = threadIdx.x & 1;
    const float si   = s_score[row];

    int rank = 0;
    const float4* s4 = reinterpret_cast<const float4*>(s_score);
    const int j4b = half * (kN / 8), j4e = j4b + kN / 8;
    for (int j4 = j4b; j4 < j4e; ++j4) {
        const float4 v = s4[j4];
        const int j = j4 * 4;
        rank += (v.x > si) || (v.x == si && (j + 0) < row);
        rank += (v.y > si) || (v.y == si && (j + 1) < row);
        rank += (v.z > si) || (v.z == si && (j + 2) < row);
        rank += (v.w > si) || (v.w == si && (j + 3) < row);
    }
    const int total = rank + __shfl_xor(rank, 1);

    if (half == 0) {
        order[(size_t)b * kN + total] = row;
        const float4 bx = reinterpret_cast<const float4*>(rois)[(size_t)b * kN + row];
        const float cy1 = fminf(bx.x, bx.z), cy2 = fmaxf(bx.x, bx.z);
        const float cx1 = fminf(bx.y, bx.w), cx2 = fmaxf(bx.y, bx.w);
        boxes_sorted[(size_t)b * kN + total] = make_float4(cy1, cx1, cy2, cx2);
    }
}

// ---------------------------------------------------------------- P2: mask
constexpr int kMaskThreads = 1024;          // 16 waves
constexpr int kRowsPerMaskBlock = 32;       // 2 rows per wave

__global__ __launch_bounds__(kMaskThreads)
void mask_kernel(const float4* __restrict__ boxes_sorted, // [B, kN]
                 unsigned int* __restrict__ mask)         // [B, kM, kMW]
{
    const int b  = blockIdx.y;
    const int r0 = blockIdx.x * kRowsPerMaskBlock;

    __shared__ float4 s_box[kM];
    __shared__ float  s_area[kM];
    for (int t = threadIdx.x; t < kM; t += kMaskThreads) {
        const float4 c = boxes_sorted[(size_t)b * kN + t];
        s_box[t]  = c;
        s_area[t] = (c.z - c.x) * (c.w - c.y);
    }
    __syncthreads();

    const int wave = threadIdx.x >> 6;
    const int lane = threadIdx.x & 63;

    for (int rr = 0; rr < 2; ++rr) {
        const int i = r0 + wave * 2 + rr;          // i < kM
        const float4 bi = s_box[i];
        const float  ai = s_area[i];
        unsigned int myw = 0u;
        for (int k = 0; k < kNCH; ++k) {           // FULL row (left part too)
            const int j = k * 64 + lane;
            const float4 bj = s_box[j];
            const float iy1 = fmaxf(bi.x, bj.x);
            const float ix1 = fmaxf(bi.y, bj.y);
            const float iy2 = fminf(bi.z, bj.z);
            const float ix2 = fminf(bi.w, bj.w);
            const float inter = fmaxf(iy2 - iy1, 0.0f) * fmaxf(ix2 - ix1, 0.0f);
            const float uni   = ai + s_area[j] - inter;
            const bool  sup   = (uni > 0.0f) && (inter / uni > kIouThr);
            const unsigned long long bal = __ballot(sup);   // bit l <-> j=k*64+l
            if ((lane >> 1) == k)
                myw = (lane & 1) ? (unsigned int)(bal >> 32) : (unsigned int)bal;
        }
        if (lane < kMW)
            mask[((size_t)b * kM + i) * kMW + lane] = myw;  // compact 80B rows
    }
}

// ---------------------------------------------------------------- P3: scan
__global__ __launch_bounds__(64, 1)
void scan_kernel(const unsigned int* __restrict__ mask,    // [B, kM, kMW]
                 const int* __restrict__ order,            // [B, kN]
                 const float4* __restrict__ boxes_sorted,  // [B, kN] canonical
                 const float* __restrict__ rois,           // [B, kN, 4] orig
                 float* __restrict__ out,                  // [B, max_out, 4]
                 int max_out)
{
    const int b    = blockIdx.x;
    const int lane = threadIdx.x;
    const unsigned int* m = mask + (size_t)b * kM * kMW;

    __shared__ int    s_keep[512];      // kept sorted-positions (max_out<=512)
    __shared__ float4 s_kbox[512];      // fallback only
    __shared__ float  s_karea[512];

    int  count   = 0;
    bool stopped = false;

    // kept-bitmap over sorted positions [0,kM): 20 uniform scalars
    unsigned int kw0=0,kw1=0,kw2=0,kw3=0,kw4=0,kw5=0,kw6=0,kw7=0,kw8=0,kw9=0,
                 kw10=0,kw11=0,kw12=0,kw13=0,kw14=0,kw15=0,kw16=0,kw17=0,
                 kw18=0,kw19=0;

    uint4 a0,a1,a2,a3,a4, b0,b1,b2,b3,b4;   // double-buffered row words

#define LOADROW(P0,P1,P2,P3,P4, CH) {                                         \
        const uint4* rp_ = reinterpret_cast<const uint4*>(                    \
            m + (size_t)((CH) * 64 + lane) * kMW);                            \
        P0 = rp_[0]; P1 = rp_[1]; P2 = rp_[2]; P3 = rp_[3]; P4 = rp_[4]; }

    // Resolve chunk CH whose row words sit in B0..B4; prefetch CH+1 into N*.
    // DW.LO/DW.HI = this row's diagonal-block words (2CH, 2CH+1).
    // KWLO/KWHI   = kept-bitmap words 2CH, 2CH+1 (written here).
#define CHUNK(B0,B1,B2,B3,B4, N0,N1,N2,N3,N4, DW, LO, HI, KWLO, KWHI, CH)     \
    if (!stopped) {                                                           \
        if ((CH) + 1 < kNCH) LOADROW(N0,N1,N2,N3,N4, (CH) + 1)                \
        const unsigned int accp_ =                                            \
            (B0.x & kw0)  | (B0.y & kw1)  | (B0.z & kw2)  | (B0.w & kw3)  |   \
            (B1.x & kw4)  | (B1.y & kw5)  | (B1.z & kw6)  | (B1.w & kw7)  |   \
            (B2.x & kw8)  | (B2.y & kw9)  | (B2.z & kw10) | (B2.w & kw11) |   \
            (B3.x & kw12) | (B3.y & kw13) | (B3.z & kw14) | (B3.w & kw15) |   \
            (B4.x & kw16) | (B4.y & kw17) | (B4.z & kw18) | (B4.w & kw19);    \
        const unsigned long long prev64_ = __ballot(accp_ != 0u);             \
        const unsigned long long mycol_ =                                     \
            (unsigned long long)(DW.LO) | ((unsigned long long)(DW.HI) << 32);\
        unsigned long long notSup_ = ~prev64_;                                \
        unsigned long long todo_   = ~0ull;                                   \
        unsigned long long kept_   = 0ull;                                    \
        while (count < max_out) {                                             \
            const unsigned long long cand_ = notSup_ & todo_;                 \
            if (!cand_) break;                                                \
            const int u_ = __builtin_ctzll(cand_);   /* lowest undecided */   \
            if (lane == 0) s_keep[count] = (CH) * 64 + u_;                    \
            ++count;                                                          \
            kept_ |= (1ull << u_);                                            \
            const unsigned long long low_ =                                   \
                (u_ == 63) ? ~0ull : ((1ull << (u_ + 1)) - 1ull);             \
            todo_ &= ~low_;                                                   \
            const unsigned long long supByU_ =                                \
                __ballot((mycol_ >> u_) & 1ull);                              \
            notSup_ &= ~(supByU_ & ~low_);       /* suppress rows > u only */ \
        }                                                                     \
        if (count >= max_out) stopped = true;                                 \
        else { KWLO = (unsigned int)kept_;                                    \
               KWHI = (unsigned int)(kept_ >> 32); }                          \
    }

    LOADROW(a0,a1,a2,a3,a4, 0)
    CHUNK(a0,a1,a2,a3,a4, b0,b1,b2,b3,b4, a0, x, y, kw0,  kw1,  0)
    CHUNK(b0,b1,b2,b3,b4, a0,a1,a2,a3,a4, b0, z, w, kw2,  kw3,  1)
    CHUNK(a0,a1,a2,a3,a4, b0,b1,b2,b3,b4, a1, x, y, kw4,  kw5,  2)
    CHUNK(b0,b1,b2,b3,b4, a0,a1,a2,a3,a4, b1, z, w, kw6,  kw7,  3)
    CHUNK(a0,a1,a2,a3,a4, b0,b1,b2,b3,b4, a2, x, y, kw8,  kw9,  4)
    CHUNK(b0,b1,b2,b3,b4, a0,a1,a2,a3,a4, b2, z, w, kw10, kw11, 5)
    CHUNK(a0,a1,a2,a3,a4, b0,b1,b2,b3,b4, a3, x, y, kw12, kw13, 6)
    CHUNK(b0,b1,b2,b3,b4, a0,a1,a2,a3,a4, b3, z, w, kw14, kw15, 7)
    CHUNK(a0,a1,a2,a3,a4, b0,b1,b2,b3,b4, a4, x, y, kw16, kw17, 8)
    CHUNK(b0,b1,b2,b3,b4, a0,a1,a2,a3,a4, b4, z, w, kw18, kw19, 9)
#undef CHUNK
#undef LOADROW

    // ---- lazy continuation past the window (correctness insurance) ----
    if (count < max_out) {
        __syncthreads();
        const float4* bsrt = boxes_sorted + (size_t)b * kN;
        for (int k = lane; k < count; k += 64) {
            const float4 c = bsrt[s_keep[k]];
            s_kbox[k]  = c;
            s_karea[k] = (c.z - c.x) * (c.w - c.y);
        }
        __syncthreads();
        for (int i = kM; i < kN && count < max_out; ++i) {
            const float4 bi = bsrt[i];
            const float  ai = (bi.z - bi.x) * (bi.w - bi.y);
            bool supb = false;
            for (int k = lane; k < count; k += 64) {
                const float4 bk = s_kbox[k];
                const float iy1 = fmaxf(bi.x, bk.x);
                const float ix1 = fmaxf(bi.y, bk.y);
                const float iy2 = fminf(bi.z, bk.z);
                const float ix2 = fminf(bi.w, bk.w);
                const float inter = fmaxf(iy2 - iy1, 0.0f) * fmaxf(ix2 - ix1, 0.0f);
                const float uni   = s_karea[k] + ai - inter;  // f32 add commutes
                supb = supb || ((uni > 0.0f) && (inter / uni > kIouThr));
            }
            if (!__any(supb)) {
                if (lane == 0) {
                    s_keep[count]  = i;
                    s_kbox[count]  = bi;
                    s_karea[count] = ai;
                }
                ++count;
            }
        }
    }

    __syncthreads();

    const float4* rois4 = reinterpret_cast<const float4*>(rois) + (size_t)b * kN;
    float4*       out4  = reinterpret_cast<float4*>(out) + (size_t)b * max_out;
    const int*    bo    = order + (size_t)b * kN;
    for (int c = lane; c < max_out; c += 64) {
        int oidx = 0;                                   // pad with orig box 0
        if (c < count) oidx = bo[s_keep[c]];
        out4[c] = rois4[oidx];
    }
}

// ------------------------------------------------- fallback (round-1 kernel)
constexpr int kFbThreads = 1024;

__global__ __launch_bounds__(kFbThreads)
void nms_fallback(const float* __restrict__ rois, const float* __restrict__ scores,
                  float* __restrict__ out, int max_out)
{
    const int b   = blockIdx.x;
    const int tid = threadIdx.x;
    __shared__ float        s_score[kN];
    __shared__ int          s_order[kN];
    __shared__ float4       s_box[kN];
    __shared__ float        s_area[kN];
    __shared__ unsigned int s_sup[kN / 32];
    __shared__ int          s_count;
    const float* brois   = rois   + (size_t)b * kN * 4;
    const float* bscores = scores + (size_t)b * kN;
    for (int i = tid; i < kN; i += kFbThreads) s_score[i] = bscores[i];
    for (int i = tid; i < kN / 32; i += kFbThreads) s_sup[i] = 0u;
    if (tid == 0) s_count = 0;
    __syncthreads();
    for (int i = tid; i < kN; i += kFbThreads) {
        const float si = s_score[i];
        int rank = 0;
        const float4* s4 = reinterpret_cast<const float4*>(s_score);
        for (int j4 = 0; j4 < kN / 4; ++j4) {
            const float4 v = s4[j4];
            const int j = j4 * 4;
            rank += (v.x > si) || (v.x == si && (j + 0) < i);
            rank += (v.y > si) || (v.y == si && (j + 1) < i);
            rank += (v.z > si) || (v.z == si && (j + 2) < i);
            rank += (v.w > si) || (v.w == si && (j + 3) < i);
        }
        s_order[rank] = i;
    }
    __syncthreads();
    for (int r = tid; r < kN; r += kFbThreads) {
        const int idx = s_order[r];
        const float4 bx = *reinterpret_cast<const float4*>(brois + (size_t)idx * 4);
        const float cy1 = fminf(bx.x, bx.z), cy2 = fmaxf(bx.x, bx.z);
        const float cx1 = fminf(bx.y, bx.w), cx2 = fmaxf(bx.y, bx.w);
        s_box[r]  = make_float4(cy1, cx1, cy2, cx2);
        s_area[r] = (cy2 - cy1) * (cx2 - cx1);
    }
    __syncthreads();
    for (int i = 0; i < kN; ++i) {
        const bool sup_i = (s_sup[i >> 5] >> (i & 31)) & 1u;
        if (!sup_i) {
            const float4 bi = s_box[i];
            const float  ai = s_area[i];
            for (int j = i + 1 + tid; j < kN; j += kFbThreads) {
                const float4 bj = s_box[j];
                const float iy1 = fmaxf(bi.x, bj.x);
                const float ix1 = fmaxf(bi.y, bj.y);
                const float iy2 = fminf(bi.z, bj.z);
                const float ix2 = fminf(bi.w, bj.w);
                const float inter = fmaxf(iy2 - iy1, 0.0f) * fmaxf(ix2 - ix1, 0.0f);
                const float uni   = ai + s_area[j] - inter;
                const float iou   = (uni > 0.0f) ? (inter / uni) : 0.0f;
                if (iou > kIouThr) atomicOr(&s_sup[j >> 5], 1u << (j & 31));
            }
            if (tid == 0) {
                const int c = s_count;
                if (c < max_out) {
                    const int oidx = s_order[i];
                    reinterpret_cast<float4*>(out)[(size_t)b * max_out + c] =
                        *reinterpret_cast<const float4*>(brois + (size_t)oidx * 4);
                }
                s_count = c + 1;
            }
        }
        __syncthreads();
        const bool stop = (s_count >= max_out);
        __syncthreads();
        if (stop) break;
    }
    const int c = min(s_count, max_out);
    const float4 pad = *reinterpret_cast<const float4*>(brois);
    for (int r = c + tid; r < max_out; r += kFbThreads) {
        reinterpret_cast<float4*>(out)[(size_t)b * max_out + r] = pad;
    }
}

// ---------------------------------------------------------------- launch
extern "C" void kernel_launch(void* const* d_in, const int* in_sizes, int n_in,
                              void* d_out, int out_size, void* d_ws, size_t ws_size,
                              hipStream_t stream)
{
    const float* rois   = (const float*)d_in[0];
    const float* scores = (const float*)d_in[1];
    float* out = (float*)d_out;

    const int B       = in_sizes[1] / kN;        // scores are [B, kN]
    const int max_out = out_size / (4 * B);      // out is [B, max_out, 4]

    const size_t maskBytes  = (size_t)B * kM * kMW * sizeof(unsigned int);
    const size_t orderBytes = (size_t)B * kN * sizeof(int);
    const size_t boxesBytes = (size_t)B * kN * sizeof(float4);

    if (ws_size >= maskBytes + orderBytes + boxesBytes && max_out <= 512) {
        unsigned int* mask  = (unsigned int*)d_ws;
        int*          order = (int*)((char*)d_ws + maskBytes);
        float4*       boxes = (float4*)((char*)d_ws + maskBytes + orderBytes);

        rank_kernel<<<dim3(kN / (kRankThreads / 2), B), dim3(kRankThreads), 0, stream>>>(
            rois, scores, order, boxes);
        mask_kernel<<<dim3(kM / kRowsPerMaskBlock, B), dim3(kMaskThreads), 0, stream>>>(
            boxes, mask);
        scan_kernel<<<dim3(B), dim3(64), 0, stream>>>(mask, order, boxes, rois, out, max_out);
    } else {
        nms_fallback<<<dim3(B), dim3(kFbThreads), 0, stream>>>(rois, scores, out, max_out);
    }
}